// Round 15
// baseline (117.771 us; speedup 1.0000x reference)
//
#include <hip/hip_runtime.h>

// Depthwise 4x4 FIR blur, pad (2,2)/(2,2), NCHW fp32.
// x: [16,256,128,128] -> out: [16,256,129,129]
//
// PRODUCER/CONSUMER wave specialization. Block = half image (64 out rows;
// s==1 also row 128), 512 thr = 8 waves. Wave 0 (producer) issues ALL 34
// 1KB global_load_lds pair-loads back-to-back (continuous deep read
// stream), then publishes progress with counted vmcnt -> LDS flag
// (pairs-ready = {6,12,18,24,30,34}), then computes rows 56..63 (+128).
// Waves 1..7 (consumers) each own 8 rows (lbase=8(wv-1)); per 2-row iter
// they spin on flag >= lbase/2+i+3 (wave-uniform) then ds_read+FMA+store.
// NO block-wide barrier in steady state (one raw s_barrier for init).
// LDS slot t = input row 64s-2+t (t=0..67); OOB rows clamp-staged, zero-
// substituted via okr->zrow redirect. Edge cols 126..128: g==31 fold.

__global__ __launch_bounds__(512) void blur_pc(
    const float* __restrict__ x,
    const float* __restrict__ kern,
    float* __restrict__ out)
{
    // 68 row slots (34 KB) + zero-row (512 B) + flag
    __shared__ __align__(16) float lds[68 * 128 + 128 + 4];

    const int tid  = threadIdx.x;
    const int bid  = blockIdx.x;
    // bijective XCD swizzle: 8192 blocks = 8 XCDs x 1024
    const int wk   = ((bid & 7) << 10) | (bid >> 3);
    const int img  = wk >> 1;
    const int s    = wk & 1;         // half: out rows [64s, 64s+64)
    const int wv   = tid >> 6;
    const int lane = tid & 63;
    const int h    = lane >> 5;      // row-within-pair
    const int g    = lane & 31;      // col group: out cols 4g-2..4g+1
    const bool lv  = (g >= 1);

    const float* __restrict__ xi = x + (size_t)img * 16384;
    float* __restrict__ oi = out + (size_t)img * 16641;

    volatile int* flag = (volatile int*)&lds[68 * 128 + 128];
    const float* const zrow = &lds[68 * 128];

    // weights first (before producer's stage stream, so vmcnt counting
    // stays conservative even if these compile to vector loads)
    float w[4][4];
#pragma unroll
    for (int p = 0; p < 4; ++p)
#pragma unroll
        for (int d = 0; d < 4; ++d)
            w[p][d] = kern[4 * p + d];
    __builtin_amdgcn_sched_barrier(0);

    // init zero-row + flag, make visible, one raw barrier
    if (tid < 128) lds[68 * 128 + tid] = 0.0f;
    if (tid == 0)  *flag = 0;
    asm volatile("s_waitcnt lgkmcnt(0)" ::: "memory");
    __builtin_amdgcn_s_barrier();

    // ---- producer: wave 0 ----
    if (wv == 0) {
        // pair p -> slots 2p,2p+1 = input rows 64s-2+2p, +1 (clamped dummy)
        for (int p = 0; p < 34; ++p) {
            int row = 64 * s - 2 + 2 * p;
            row = row < 0 ? 0 : (row > 126 ? 126 : row);
            const float* src = xi + (size_t)row * 128 + (lane << 2);
            const float* dst = &lds[p * 256];
            __builtin_amdgcn_global_load_lds(
                (const __attribute__((address_space(1))) unsigned int*)src,
                (__attribute__((address_space(3))) unsigned int*)dst,
                16, 0, 0);
        }
        __builtin_amdgcn_sched_barrier(0);
#define PUB(NSTR, V) do {                                                    \
        asm volatile("s_waitcnt vmcnt(" NSTR ")" ::: "memory");              \
        __builtin_amdgcn_sched_barrier(0);                                   \
        if (lane == 0) *flag = (V);                                          \
    } while (0)
        PUB("28", 6);  PUB("22", 12); PUB("16", 18);
        PUB("10", 24); PUB("4", 30);  PUB("0", 34);
#undef PUB
    }

    // ---- compute (all waves; producer takes the tail rows) ----
    const int lbase = (wv == 0) ? 56 : 8 * (wv - 1);   // local rows lbase..+7
    const int r0    = lbase + h;                       // this thread's row 0

    float xv[4][8];

    // slot t holds input row 64s-2+t; ring idx = (t - r0) & 3
#define LLOAD(S, T) do {                                                     \
        const int t_ = (T);                                                  \
        const float* pb_ = &lds[t_ * 128 + 4 * g];                           \
        const bool okr_ = (unsigned)(64 * s - 2 + t_) < 128u;                \
        const float* pa_  = (okr_ && lv) ? (pb_ - 4) : zrow;                 \
        const float* pbv_ = okr_ ? pb_ : zrow;                               \
        float4 a_ = *(const float4*)pa_;                                     \
        float4 b_ = *(const float4*)pbv_;                                    \
        xv[S][0] = a_.x; xv[S][1] = a_.y; xv[S][2] = a_.z; xv[S][3] = a_.w;  \
        xv[S][4] = b_.x; xv[S][5] = b_.y; xv[S][6] = b_.z; xv[S][7] = b_.w;  \
    } while (0)

#define ACCP(S, P) do {                                                      \
        o0 = fmaf(xv[S][0], w[P][0], o0);                                    \
        o1 = fmaf(xv[S][1], w[P][0], o1);                                    \
        o2 = fmaf(xv[S][2], w[P][0], o2);                                    \
        o3 = fmaf(xv[S][3], w[P][0], o3);                                    \
        o0 = fmaf(xv[S][1], w[P][1], o0);                                    \
        o1 = fmaf(xv[S][2], w[P][1], o1);                                    \
        o2 = fmaf(xv[S][3], w[P][1], o2);                                    \
        o3 = fmaf(xv[S][4], w[P][1], o3);                                    \
        o0 = fmaf(xv[S][2], w[P][2], o0);                                    \
        o1 = fmaf(xv[S][3], w[P][2], o1);                                    \
        o2 = fmaf(xv[S][4], w[P][2], o2);                                    \
        o3 = fmaf(xv[S][5], w[P][2], o3);                                    \
        o0 = fmaf(xv[S][3], w[P][3], o0);                                    \
        o1 = fmaf(xv[S][4], w[P][3], o1);                                    \
        o2 = fmaf(xv[S][5], w[P][3], o2);                                    \
        o3 = fmaf(xv[S][6], w[P][3], o3);                                    \
    } while (0)

#define XROW(S, P) do {                                                      \
        e0 = fmaf(xv[S][4], w[P][0], e0);                                    \
        e0 = fmaf(xv[S][5], w[P][1], e0);                                    \
        e0 = fmaf(xv[S][6], w[P][2], e0);                                    \
        e0 = fmaf(xv[S][7], w[P][3], e0);                                    \
        e1 = fmaf(xv[S][5], w[P][0], e1);                                    \
        e1 = fmaf(xv[S][6], w[P][1], e1);                                    \
        e1 = fmaf(xv[S][7], w[P][2], e1);                                    \
        e2 = fmaf(xv[S][6], w[P][0], e2);                                    \
        e2 = fmaf(xv[S][7], w[P][1], e2);                                    \
    } while (0)

    // compute local out row LR from ring slots (SA,SB,SC,SD); store if EN
#define CS(SA, SB, SC, SD, LR, EN) do {                                      \
        float o0 = 0.f, o1 = 0.f, o2 = 0.f, o3 = 0.f;                        \
        ACCP(SA, 0); ACCP(SB, 1); ACCP(SC, 2); ACCP(SD, 3);                  \
        if (EN) {                                                            \
            float* po_ = oi + (size_t)(64 * s + (LR)) * 129 + 4 * g - 2;     \
            if (lv) { po_[0] = o0; po_[1] = o1; }                            \
            po_[2] = o2;                                                     \
            po_[3] = o3;                                                     \
            if (g == 31) {                                                   \
                float e0 = 0.f, e1 = 0.f, e2 = 0.f;                          \
                XROW(SA, 0); XROW(SB, 1); XROW(SC, 2); XROW(SD, 3);          \
                po_[4] = e0; po_[5] = e1; po_[6] = e2;  /* cols 126..128 */  \
            }                                                                \
        }                                                                    \
    } while (0)

    // spin until pairs [0, NEED) are published (wave-uniform NEED)
#define SPIN(NEED) do {                                                      \
        while (*flag < (NEED)) __builtin_amdgcn_s_sleep(1);                  \
        asm volatile("" ::: "memory");                                       \
        __builtin_amdgcn_sched_barrier(0);                                   \
    } while (0)

    // iter i computes local row lbase+2i+h; slots lbase+2i+h .. +3;
    // max slot (h=1) = lbase+2i+4 -> pair (lbase+2i+4)/2 -> need lbase/2+i+3
    SPIN(lbase / 2 + 3);
    LLOAD(0, r0 + 0); LLOAD(1, r0 + 1); LLOAD(2, r0 + 2); LLOAD(3, r0 + 3);
    CS(0, 1, 2, 3, lbase + 0 + h, true);

    SPIN(lbase / 2 + 4);
    LLOAD(0, r0 + 4); LLOAD(1, r0 + 5);
    CS(2, 3, 0, 1, lbase + 2 + h, true);

    SPIN(lbase / 2 + 5);
    LLOAD(2, r0 + 6); LLOAD(3, r0 + 7);
    CS(0, 1, 2, 3, lbase + 4 + h, true);

    SPIN(lbase / 2 + 6);
    LLOAD(0, r0 + 8); LLOAD(1, r0 + 9);
    CS(2, 3, 0, 1, lbase + 6 + h, true);

    // out row 128 (s==1, producer wave): slots 64..67 (rows 126..129;
    // 128,129 zero-substituted). flag already 34.
    if (s == 1 && wv == 0) {
        LLOAD(0, 64); LLOAD(1, 65); LLOAD(2, 66); LLOAD(3, 67);
        CS(0, 1, 2, 3, 64, (h == 0));
    }

#undef LLOAD
#undef ACCP
#undef XROW
#undef CS
#undef SPIN
}

extern "C" void kernel_launch(void* const* d_in, const int* in_sizes, int n_in,
                              void* d_out, int out_size, void* d_ws, size_t ws_size,
                              hipStream_t stream) {
    const float* x    = (const float*)d_in[0];
    const float* kern = (const float*)d_in[1];
    float* out        = (float*)d_out;

    // 4096 images * 2 halves = 8192 blocks
    dim3 grid(8192), block(512);
    hipLaunchKernelGGL(blur_pc, grid, block, 0, stream, x, kern, out);
}

// Round 16
// 110.106 us; speedup vs baseline: 1.0696x; 1.0696x over previous
//
#include <hip/hip_runtime.h>

// Depthwise 4x4 FIR blur, pad (2,2)/(2,2), NCHW fp32.
// x: [16,256,128,128] -> out: [16,256,129,129]
//
// CHAMPION (R8, 109.7 us) — final revert. Block = half image (64 output
// rows; s==1 also row 128), 512 threads. Stage all 66 valid input rows
// (33 x 1KB global_load_lds pairs) + zero pad rows + zero-row, ONE
// __syncthreads, then compute. Thread = 4 output cols (g=tid&31) x 4 rows
// (c=tid>>5) via ds_read_b128 register ring. Stores bounce through a
// wave-local LDS row buffer (ds_write_b128 + wave-local lgkmcnt(0)) and
// flush as dense per-lane dword stores (32 contiguous dwords/instruction).

__global__ __launch_bounds__(512) void blur_half3(
    const float* __restrict__ x,
    const float* __restrict__ kern,
    float* __restrict__ out)
{
    // input rows: slots 0..67 (+ zero-row slot 68) = 8832 floats;
    // out bounce: 8 waves x 2 halves x 132 floats = 2112 floats. 43.8 KB.
    __shared__ __align__(16) float lds[69 * 128 + 8 * 264];

    const int tid  = threadIdx.x;
    const int bid  = blockIdx.x;
    // bijective XCD swizzle: 8192 blocks = 8 XCDs x 1024
    const int wk   = ((bid & 7) << 10) | (bid >> 3);
    const int img  = wk >> 1;
    const int s    = wk & 1;         // half: out rows [64s, 64s+64)
    const int wv   = tid >> 6;
    const int lane = tid & 63;

    const float* __restrict__ xi = x + (size_t)img * (128 * 128);
    float* __restrict__ oi = out + (size_t)img * (129 * 129);

    // ---- stage: pair p = LDS slots (2p, 2p+1) = input rows 64s-2+2p, +1.
    // Valid pairs: s==0 -> p=1..33 (rows 0..65); s==1 -> p=0..32 (rows 62..127).
    const int P0 = s ? 0 : 1;
    const int P1 = s ? 32 : 33;
    for (int p = P0 + wv; p <= P1; p += 8) {
        const int row = 64 * s - 2 + 2 * p;
        const float* src = xi + (size_t)row * 128 + (lane << 2);
        const float* dst = &lds[p * 256];
        __builtin_amdgcn_global_load_lds(
            (const __attribute__((address_space(1))) unsigned int*)src,
            (__attribute__((address_space(3))) unsigned int*)dst, 16, 0, 0);
    }
    // zero pad rows + zero-row (disjoint from staged slots)
    if (tid < 256) {
        if (s) lds[8448 + tid] = 0.0f;   // slots 66,67 (rows 128,129)
        else   lds[tid]        = 0.0f;   // slots 0,1   (rows -2,-1)
    } else if (tid < 384) {
        lds[8448 + tid] = 0.0f;          // 8704..8831 = slot 68 (zero-row)
    }

    // 4x4 weights; uniform -> SGPRs
    float w[4][4];
#pragma unroll
    for (int p = 0; p < 4; ++p)
#pragma unroll
        for (int q = 0; q < 4; ++q)
            w[p][q] = kern[4 * p + q];

    __syncthreads();

    // ---- compute ----
    const int c  = tid >> 5;         // row subchunk 0..15 (4 rows each)
    const int g  = tid & 31;         // col group: out cols 4g-2 .. 4g+1
    const bool lv = (g >= 1);
    const float* const zrow = &lds[68 * 128];
    // wave-local out bounce buffer: [wv][half][132]; col j at idx j+2
    float* const obuf = &lds[69 * 128 + wv * 264 + (c & 1) * 132];

    float xv[4][8];

    // out row i = 64s+4c+j window = slots 4c+j .. 4c+j+3; a = cols 4g-4..4g-1
    // (zero-row for g==0), b = cols 4g..4g+3. Both reads unconditional.
#define LLOAD(S, KK) do {                                                    \
        const float* pb_ = &lds[(4 * c + (KK)) * 128 + 4 * g];               \
        const float* pa_ = lv ? (pb_ - 4) : zrow;                            \
        float4 a_ = *(const float4*)pa_;                                     \
        float4 b_ = *(const float4*)pb_;                                     \
        xv[S][0] = a_.x; xv[S][1] = a_.y; xv[S][2] = a_.z; xv[S][3] = a_.w;  \
        xv[S][4] = b_.x; xv[S][5] = b_.y; xv[S][6] = b_.z; xv[S][7] = b_.w;  \
    } while (0)

#define ACCP(S, P) do {                                                      \
        o0 = fmaf(xv[S][0], w[P][0], o0);                                    \
        o1 = fmaf(xv[S][1], w[P][0], o1);                                    \
        o2 = fmaf(xv[S][2], w[P][0], o2);                                    \
        o3 = fmaf(xv[S][3], w[P][0], o3);                                    \
        o0 = fmaf(xv[S][1], w[P][1], o0);                                    \
        o1 = fmaf(xv[S][2], w[P][1], o1);                                    \
        o2 = fmaf(xv[S][3], w[P][1], o2);                                    \
        o3 = fmaf(xv[S][4], w[P][1], o3);                                    \
        o0 = fmaf(xv[S][2], w[P][2], o0);                                    \
        o1 = fmaf(xv[S][3], w[P][2], o1);                                    \
        o2 = fmaf(xv[S][4], w[P][2], o2);                                    \
        o3 = fmaf(xv[S][5], w[P][2], o3);                                    \
        o0 = fmaf(xv[S][3], w[P][3], o0);                                    \
        o1 = fmaf(xv[S][4], w[P][3], o1);                                    \
        o2 = fmaf(xv[S][5], w[P][3], o2);                                    \
        o3 = fmaf(xv[S][6], w[P][3], o3);                                    \
    } while (0)

    // edge cols 126..128 for g==31 (xv[.][4..7] = input cols 124..127)
#define XROW(S, P) do {                                                      \
        e0 = fmaf(xv[S][4], w[P][0], e0);                                    \
        e0 = fmaf(xv[S][5], w[P][1], e0);                                    \
        e0 = fmaf(xv[S][6], w[P][2], e0);                                    \
        e0 = fmaf(xv[S][7], w[P][3], e0);                                    \
        e1 = fmaf(xv[S][5], w[P][0], e1);                                    \
        e1 = fmaf(xv[S][6], w[P][1], e1);                                    \
        e1 = fmaf(xv[S][7], w[P][2], e1);                                    \
        e2 = fmaf(xv[S][6], w[P][0], e2);                                    \
        e2 = fmaf(xv[S][7], w[P][1], e2);                                    \
    } while (0)

    // CS: compute row 64s+4c+J, bounce to obuf, flush densely.
#define CS(SA, SB, SC, SD, J) do {                                           \
        float o0 = 0.f, o1 = 0.f, o2 = 0.f, o3 = 0.f;                        \
        ACCP(SA, 0); ACCP(SB, 1); ACCP(SC, 2); ACCP(SD, 3);                  \
        *(float4*)&obuf[4 * g] = make_float4(o0, o1, o2, o3);                \
        if (g == 31) {                                                       \
            float e0 = 0.f, e1 = 0.f, e2 = 0.f;                              \
            XROW(SA, 0); XROW(SB, 1); XROW(SC, 2); XROW(SD, 3);              \
            *(float2*)&obuf[128] = make_float2(e0, e1);  /* cols 126,127 */  \
            obuf[130] = e2;                              /* col  128     */  \
        }                                                                    \
        asm volatile("s_waitcnt lgkmcnt(0)" ::: "memory");                   \
        __builtin_amdgcn_sched_barrier(0);                                   \
        {                                                                    \
            float* po_ = oi + (size_t)(64 * s + 4 * c + (J)) * 129;          \
            _Pragma("unroll")                                                \
            for (int k_ = 0; k_ < 4; ++k_)                                   \
                po_[g + 32 * k_] = obuf[2 + g + 32 * k_];                    \
            if (g == 0) po_[128] = obuf[130];                                \
        }                                                                    \
    } while (0)

    {
        LLOAD(0, 0); LLOAD(1, 1); LLOAD(2, 2); LLOAD(3, 3);
        CS(0, 1, 2, 3, 0); LLOAD(0, 4);
        CS(1, 2, 3, 0, 1); LLOAD(1, 5);
        CS(2, 3, 0, 1, 2); LLOAD(2, 6);
        CS(3, 0, 1, 2, 3);
        if (s == 1 && c == 15) {                 // out row 128: slots 64..67
            LLOAD(3, 7);
            CS(0, 1, 2, 3, 4);
        }
    }

#undef LLOAD
#undef ACCP
#undef XROW
#undef CS
}

extern "C" void kernel_launch(void* const* d_in, const int* in_sizes, int n_in,
                              void* d_out, int out_size, void* d_ws, size_t ws_size,
                              hipStream_t stream) {
    const float* x    = (const float*)d_in[0];
    const float* kern = (const float*)d_in[1];
    float* out        = (float*)d_out;

    // 4096 images * 2 halves = 8192 blocks
    dim3 grid(8192), block(512);
    hipLaunchKernelGGL(blur_half3, grid, block, 0, stream, x, kern, out);
}